// Round 11
// baseline (225.662 us; speedup 1.0000x reference)
//
#include <hip/hip_runtime.h>
#include <hip/hip_bf16.h>
#include <stdint.h>

#define B_ 4
#define T_ 2048
#define D_ 1024
#define H_ 16
#define DK_ 64
#define M_ (B_*T_)   // 8192

typedef __attribute__((ext_vector_type(8))) short bf16x8;
typedef __attribute__((ext_vector_type(4))) short bf16x4;
typedef __attribute__((ext_vector_type(4))) float f32x4;
typedef __hip_bfloat16 bf16;

__device__ __forceinline__ void gld_lds16(const bf16* g, bf16* l) {
  __builtin_amdgcn_global_load_lds((const __attribute__((address_space(1))) void*)g,
                                   (__attribute__((address_space(3))) void*)l,
                                   16, 0, 0);
}

__device__ __forceinline__ short bfbits(float f) {
  union { bf16 h; short s; } u; u.h = __float2bfloat16(f); return u.s;
}

// ---------------------------------------------------------------------------
// fp32 -> bf16 convert, WEIGHTS ONLY. q/k/v conversion fused into proj_qkv.
// ---------------------------------------------------------------------------
__global__ __launch_bounds__(256) void cvt_w(
    const float* __restrict__ wq, const float* __restrict__ wk,
    const float* __restrict__ wv, const float* __restrict__ wo,
    bf16* __restrict__ wqb, bf16* __restrict__ wkb,
    bf16* __restrict__ wvb, bf16* __restrict__ wob) {
  int gid = blockIdx.x * 256 + threadIdx.x;   // 0 .. 1048575 (float4 units)
  int s = gid >> 18, off = gid & 262143;
  const float* src = (s == 0) ? wq : (s == 1) ? wk : (s == 2) ? wv : wo;
  bf16* dst = (s == 0) ? wqb : (s == 1) ? wkb : (s == 2) ? wvb : wob;
  float4 val = reinterpret_cast<const float4*>(src)[off];
  union { ushort4 u; bf16 h[4]; } o;
  o.h[0] = __float2bfloat16(val.x);
  o.h[1] = __float2bfloat16(val.y);
  o.h[2] = __float2bfloat16(val.z);
  o.h[3] = __float2bfloat16(val.w);
  reinterpret_cast<ushort4*>(dst)[off] = o.u;
}

// ---------------------------------------------------------------------------
// Fused QKV projection, 256x128 tile, 512 threads, INPUT fp32 READ FUSED.
// T14-correct schedule: prologue issues tile-0 fp32 loads into regs; each
// K-step does {ds_write bf16(regs) + weight gld_lds} -> barrier ->
// {issue tile j+1 fp32 loads} -> MFMA(tile j) -> barrier. The prefetch is
// in flight across the whole MFMA phase, so its latency is hidden (unlike
// round 9, where issue and consume were in the same phase).
//  z=0: Qh = (q @ Wq^T + bq)*scale ; z=1: Kh ; z=2: Vt (A=Wv, B=v fp32)
// ---------------------------------------------------------------------------
__global__ __launch_bounds__(512) void proj_qkv(
    const float* __restrict__ qf, const float* __restrict__ kf, const float* __restrict__ vf,
    const bf16* __restrict__ Wqb, const bf16* __restrict__ Wkb, const bf16* __restrict__ Wvb,
    const float* __restrict__ bq, const float* __restrict__ bk, const float* __restrict__ bv,
    bf16* __restrict__ Qh, bf16* __restrict__ Kh, bf16* __restrict__ Vt) {
  constexpr int K = 1024;
  constexpr int BK = 64;
  __shared__ __align__(16) bf16 As[256 * BK];
  __shared__ __align__(16) bf16 Bs[128 * BK];

  const int z = blockIdx.z;
  const bool vt = (z == 2);
  const float* Afp = (z == 0) ? qf : kf;    // fp32 input, A-side (z<2)
  const float* Bfp = vf;                    // fp32 input, B-side (z==2)
  const bf16*  Wa  = Wvb;                   // bf16 weight, A-side (z==2)
  const bf16*  Wb  = (z == 0) ? Wqb : Wkb;  // bf16 weight, B-side (z<2)
  const float* bias = (z == 0) ? bq : (z == 1) ? bk : bv;
  bf16* out = (z == 0) ? Qh : (z == 1) ? Kh : Vt;
  const float scale = (z == 0) ? 0.125f * 1.4426950408889634f : 1.0f;

  int bm, bn;
  if (vt) { int flat = blockIdx.x + 32 * blockIdx.y; bm = flat >> 6; bn = flat & 63; }
  else    { bm = blockIdx.x; bn = blockIdx.y; }

  const int tid = threadIdx.x;
  const int w = tid >> 6, l = tid & 63;
  const int wm = w >> 1, wn = w & 1;
  const int lr = l & 15, lk = l >> 4;

  f32x4 acc[4][4] = {};
  float4 areg[8];   // !vt : 256x64 fp32 tile, 8 float4/thread
  float4 breg[4];   // vt  : 128x64 fp32 tile, 4 float4/thread

  // prologue: issue tile-0 input loads
  if (!vt) {
#pragma unroll
    for (int i = 0; i < 8; ++i) {
      int qi = i * 512 + tid, row = qi >> 4, c4 = qi & 15;
      areg[i] = *reinterpret_cast<const float4*>(Afp + (size_t)(bm * 256 + row) * K + c4 * 4);
    }
  } else {
#pragma unroll
    for (int i = 0; i < 4; ++i) {
      int qi = i * 512 + tid, row = qi >> 4, c4 = qi & 15;
      breg[i] = *reinterpret_cast<const float4*>(Bfp + (size_t)(bn * 128 + row) * K + c4 * 4);
    }
  }

  for (int k0 = 0; k0 < K; k0 += BK) {
    // ---- write staged input (bf16, swizzled) + weight gld_lds ----
    if (!vt) {
#pragma unroll
      for (int i = 0; i < 8; ++i) {
        int qi = i * 512 + tid, row = qi >> 4, c4 = qi & 15;
        bf16x4 pk;
        pk[0] = bfbits(areg[i].x); pk[1] = bfbits(areg[i].y);
        pk[2] = bfbits(areg[i].z); pk[3] = bfbits(areg[i].w);
        int s16 = (c4 >> 1) ^ (row & 7);
        *reinterpret_cast<bf16x4*>((char*)As + row * 128 + s16 * 16 + (c4 & 1) * 8) = pk;
      }
#pragma unroll
      for (int i = 0; i < 2; ++i) {
        int p = i * 512 + tid, row = p >> 3, so = (p & 7) ^ (row & 7);
        gld_lds16(Wb + (size_t)(bn * 128 + row) * K + k0 + so * 8, &Bs[p * 8]);
      }
    } else {
#pragma unroll
      for (int i = 0; i < 4; ++i) {
        int p = i * 512 + tid, row = p >> 3, so = (p & 7) ^ (row & 7);
        gld_lds16(Wa + (size_t)(bm * 256 + row) * K + k0 + so * 8, &As[p * 8]);
      }
#pragma unroll
      for (int i = 0; i < 4; ++i) {
        int qi = i * 512 + tid, row = qi >> 4, c4 = qi & 15;
        bf16x4 pk;
        pk[0] = bfbits(breg[i].x); pk[1] = bfbits(breg[i].y);
        pk[2] = bfbits(breg[i].z); pk[3] = bfbits(breg[i].w);
        int s16 = (c4 >> 1) ^ (row & 7);
        *reinterpret_cast<bf16x4*>((char*)Bs + row * 128 + s16 * 16 + (c4 & 1) * 8) = pk;
      }
    }
    __syncthreads();

    // ---- issue NEXT tile's input loads (in flight across the MFMA phase) ----
    if (k0 + BK < K) {
      if (!vt) {
#pragma unroll
        for (int i = 0; i < 8; ++i) {
          int qi = i * 512 + tid, row = qi >> 4, c4 = qi & 15;
          areg[i] = *reinterpret_cast<const float4*>(Afp + (size_t)(bm * 256 + row) * K + (k0 + BK) + c4 * 4);
        }
      } else {
#pragma unroll
        for (int i = 0; i < 4; ++i) {
          int qi = i * 512 + tid, row = qi >> 4, c4 = qi & 15;
          breg[i] = *reinterpret_cast<const float4*>(Bfp + (size_t)(bn * 128 + row) * K + (k0 + BK) + c4 * 4);
        }
      }
    }

    // ---- MFMA on tile k0 ----
#pragma unroll
    for (int kk = 0; kk < 2; ++kk) {
      bf16x8 af[4], bfr[4];
#pragma unroll
      for (int m = 0; m < 4; ++m) {
        int row = wm * 64 + m * 16 + lr;
        int slot = (kk * 4 + lk) ^ (row & 7);
        af[m] = *reinterpret_cast<const bf16x8*>(&As[row * BK + slot * 8]);
      }
#pragma unroll
      for (int n = 0; n < 4; ++n) {
        int row = wn * 64 + n * 16 + lr;
        int slot = (kk * 4 + lk) ^ (row & 7);
        bfr[n] = *reinterpret_cast<const bf16x8*>(&Bs[row * BK + slot * 8]);
      }
#pragma unroll
      for (int m = 0; m < 4; ++m)
#pragma unroll
        for (int n = 0; n < 4; ++n)
          acc[m][n] = __builtin_amdgcn_mfma_f32_16x16x32_bf16(af[m], bfr[n], acc[m][n], 0, 0, 0);
    }
    __syncthreads();
  }

  const int crow0 = bm * 256 + wm * 64;
  const int ccol0 = bn * 128 + wn * 64;
#pragma unroll
  for (int m = 0; m < 4; ++m) {
#pragma unroll
    for (int n = 0; n < 4; ++n) {
#pragma unroll
      for (int r = 0; r < 4; ++r) {
        const int row = crow0 + m * 16 + lk * 4 + r;
        const int col = ccol0 + n * 16 + lr;
        if (!vt) {
          float vv = (acc[m][n][r] + bias[col]) * scale;
          size_t idx = (((size_t)(row >> 11) * H_ + (col >> 6)) * T_ + (row & (T_ - 1))) * DK_ + (col & (DK_ - 1));
          out[idx] = __float2bfloat16(vv);
        } else {
          float vv = acc[m][n][r] + bias[row];
          size_t idx = (size_t)(col >> 11) * ((size_t)H_ * DK_ * T_) + (size_t)row * T_ + (col & (T_ - 1));
          out[idx] = __float2bfloat16(vv);
        }
      }
    }
  }
}

// ---------------------------------------------------------------------------
// Output GEMM (fp32 out), 256x128 tile, 512 threads  [round-8 form]
// ---------------------------------------------------------------------------
__global__ __launch_bounds__(512) void gemm_out(const bf16* __restrict__ A,
                                                const bf16* __restrict__ Bm,
                                                const float* __restrict__ bias,
                                                float* __restrict__ Cout) {
  constexpr int K = 1024;
  constexpr int BK = 64;
  __shared__ __align__(16) bf16 As[256 * BK];
  __shared__ __align__(16) bf16 Bs[128 * BK];

  const int bm = blockIdx.x;
  const int bn = blockIdx.y;
  const int tid = threadIdx.x;
  const int w = tid >> 6, l = tid & 63;
  const int wm = w >> 1, wn = w & 1;
  const int lr = l & 15, lk = l >> 4;

  f32x4 acc[4][4] = {};

  for (int k0 = 0; k0 < K; k0 += BK) {
#pragma unroll
    for (int i = 0; i < 4; ++i) {
      int p = i * 512 + tid;
      int row = p >> 3;
      int so = (p & 7) ^ (row & 7);
      gld_lds16(A + (size_t)(bm * 256 + row) * K + k0 + so * 8, &As[p * 8]);
    }
#pragma unroll
    for (int i = 0; i < 2; ++i) {
      int p = i * 512 + tid;
      int row = p >> 3;
      int so = (p & 7) ^ (row & 7);
      gld_lds16(Bm + (size_t)(bn * 128 + row) * K + k0 + so * 8, &Bs[p * 8]);
    }
    __syncthreads();

#pragma unroll
    for (int kk = 0; kk < 2; ++kk) {
      bf16x8 af[4], bfr[4];
#pragma unroll
      for (int m = 0; m < 4; ++m) {
        int row = wm * 64 + m * 16 + lr;
        int slot = (kk * 4 + lk) ^ (row & 7);
        af[m] = *reinterpret_cast<const bf16x8*>(&As[row * BK + slot * 8]);
      }
#pragma unroll
      for (int n = 0; n < 4; ++n) {
        int row = wn * 64 + n * 16 + lr;
        int slot = (kk * 4 + lk) ^ (row & 7);
        bfr[n] = *reinterpret_cast<const bf16x8*>(&Bs[row * BK + slot * 8]);
      }
#pragma unroll
      for (int m = 0; m < 4; ++m)
#pragma unroll
        for (int n = 0; n < 4; ++n)
          acc[m][n] = __builtin_amdgcn_mfma_f32_16x16x32_bf16(af[m], bfr[n], acc[m][n], 0, 0, 0);
    }
    __syncthreads();
  }

  const int crow0 = bm * 256 + wm * 64;
  const int ccol0 = bn * 128 + wn * 64;
#pragma unroll
  for (int m = 0; m < 4; ++m) {
#pragma unroll
    for (int n = 0; n < 4; ++n) {
#pragma unroll
      for (int r = 0; r < 4; ++r) {
        const int row = crow0 + m * 16 + lk * 4 + r;
        const int col = ccol0 + n * 16 + lr;
        Cout[(size_t)row * D_ + col] = acc[m][n][r] + bias[col];
      }
    }
  }
}

// ---------------------------------------------------------------------------
// Causal flash attention — EXACT round-8 v8 (78 µs measured): fixed-shift
// softmax, 4 blocks/CU, KVBLK=64, dbuf LDS staging, swapped-operand MFMAs,
// task pairs {pp, 31-pp}.
// ---------------------------------------------------------------------------
__global__ __launch_bounds__(256, 4) void attn_fwd(const bf16* __restrict__ Qh,
                                                   const bf16* __restrict__ Kh,
                                                   const bf16* __restrict__ Vt,
                                                   bf16* __restrict__ ctx) {
  __shared__ __align__(16) bf16 Kbuf[2][64 * 64];
  __shared__ __align__(16) bf16 Vbuf[2][64 * 64];
  __shared__ __align__(16) char Ps[4][16 * 128];

  const int tid = threadIdx.x, w = tid >> 6, l = tid & 63;
  const int lr = l & 15, lk = l >> 4;
  const int bid = blockIdx.x;
  const int xcd = bid & 7, local = bid >> 3;
  const int hsub = local >> 4;
  const int pp = local & 15;
  char* Pw = &Ps[w][0];

  const int head = xcd * 8 + hsub;
  const bf16* Qb = Qh + (size_t)head * T_ * DK_;
  const bf16* Kb = Kh + (size_t)head * T_ * DK_;
  const bf16* Vb = Vt + (size_t)head * DK_ * T_;
  const int bb = head >> 4, hh = head & 15;

#pragma unroll 1
  for (int ti = 0; ti < 2; ++ti) {
    const int t = ti ? (31 - pp) : pp;
    const int r0 = t * 64;
    const int ntiles = t + 1;
    const int qrow = r0 + w * 16 + lr;

    const bf16* qp = Qb + (size_t)qrow * DK_ + lk * 8;
    bf16x8 qf0 = *reinterpret_cast<const bf16x8*>(qp);
    bf16x8 qf1 = *reinterpret_cast<const bf16x8*>(qp + 32);

    f32x4 oacc[4] = {};
    float srow = 0.f;

#pragma unroll
    for (int i = 0; i < 2; ++i) {
      int p = i * 256 + tid;
      int row = p >> 3;
      int so = (p & 7) ^ (row & 7);
      gld_lds16(Kb + (size_t)row * DK_ + so * 8, &Kbuf[0][p * 8]);
      gld_lds16(Vb + (size_t)row * T_ + so * 8, &Vbuf[0][p * 8]);
    }
    __syncthreads();

    int buf = 0;
#pragma unroll 1
    for (int j = 0; j < ntiles; ++j) {
      if (j + 1 < ntiles) {
        const int k0n = (j + 1) * 64;
#pragma unroll
        for (int i = 0; i < 2; ++i) {
          int p = i * 256 + tid;
          int row = p >> 3;
          int so = (p & 7) ^ (row & 7);
          gld_lds16(Kb + (size_t)(k0n + row) * DK_ + so * 8, &Kbuf[buf ^ 1][p * 8]);
          gld_lds16(Vb + (size_t)row * T_ + k0n + so * 8, &Vbuf[buf ^ 1][p * 8]);
        }
      }

      f32x4 sacc[4] = {};
      __builtin_amdgcn_s_setprio(1);
#pragma unroll
      for (int n = 0; n < 4; ++n) {
        int row = n * 16 + lr;
        int s0 = lk ^ (row & 7);
        int s1 = (4 + lk) ^ (row & 7);
        bf16x8 kf0 = *reinterpret_cast<const bf16x8*>(&Kbuf[buf][row * 64 + s0 * 8]);
        bf16x8 kf1 = *reinterpret_cast<const bf16x8*>(&Kbuf[buf][row * 64 + s1 * 8]);
        sacc[n] = __builtin_amdgcn_mfma_f32_16x16x32_bf16(kf0, qf0, sacc[n], 0, 0, 0);
        sacc[n] = __builtin_amdgcn_mfma_f32_16x16x32_bf16(kf1, qf1, sacc[n], 0, 0, 0);
      }
      __builtin_amdgcn_s_setprio(0);

      if (j == ntiles - 1) {
#pragma unroll
        for (int n = 0; n < 4; ++n)
#pragma unroll
          for (int r = 0; r < 4; ++r)
            if (j * 64 + n * 16 + lk * 4 + r > qrow) sacc[n][r] = -1e30f;
      }

      float ts = 0.f;
#pragma unroll
      for (int n = 0; n < 4; ++n) {
        float p0 = __builtin_exp2f(sacc[n][0]);
        float p1 = __builtin_exp2f(sacc[n][1]);
        float p2 = __builtin_exp2f(sacc[n][2]);
        float p3 = __builtin_exp2f(sacc[n][3]);
        ts += (p0 + p1) + (p2 + p3);
        bf16x4 pk;
        pk[0] = bfbits(p0); pk[1] = bfbits(p1); pk[2] = bfbits(p2); pk[3] = bfbits(p3);
        int swz = (n * 2 + (lk >> 1)) ^ (lr & 7);
        *reinterpret_cast<bf16x4*>(Pw + lr * 128 + swz * 16 + (lk & 1) * 8) = pk;
      }
      ts += __shfl_xor(ts, 16, 64);
      ts += __shfl_xor(ts, 32, 64);
      srow += ts;

      bf16x8 pa0 = *reinterpret_cast<const bf16x8*>(Pw + lr * 128 + ((lk ^ (lr & 7)) << 4));
      bf16x8 pa1 = *reinterpret_cast<const bf16x8*>(Pw + lr * 128 + (((4 + lk) ^ (lr & 7)) << 4));

      __builtin_amdgcn_s_setprio(1);
#pragma unroll
      for (int n = 0; n < 4; ++n) {
        int row = n * 16 + lr;
        int s0 = lk ^ (row & 7);
        int s1 = (4 + lk) ^ (row & 7);
        bf16x8 vf0 = *reinterpret_cast<const bf16x8*>(&Vbuf[buf][row * 64 + s0 * 8]);
        bf16x8 vf1 = *reinterpret_cast<const bf16x8*>(&Vbuf[buf][row * 64 + s1 * 8]);
        oacc[n] = __builtin_amdgcn_mfma_f32_16x16x32_bf16(vf0, pa0, oacc[n], 0, 0, 0);
        oacc[n] = __builtin_amdgcn_mfma_f32_16x16x32_bf16(vf1, pa1, oacc[n], 0, 0, 0);
      }
      __builtin_amdgcn_s_setprio(0);

      __syncthreads();
      buf ^= 1;
    }

    const float inv = 1.0f / srow;
#pragma unroll
    for (int n = 0; n < 4; ++n) {
      bf16x4 pk;
#pragma unroll
      for (int r = 0; r < 4; ++r) pk[r] = bfbits(oacc[n][r] * inv);
      *reinterpret_cast<bf16x4*>(&ctx[((size_t)(bb * T_ + qrow)) * D_ + hh * DK_ + n * 16 + lk * 4]) = pk;
    }
    __syncthreads();
  }
}

// ---------------------------------------------------------------------------
// launch
// ---------------------------------------------------------------------------
extern "C" void kernel_launch(void* const* d_in, const int* in_sizes, int n_in,
                              void* d_out, int out_size, void* d_ws, size_t ws_size,
                              hipStream_t stream) {
  const float* q  = (const float*)d_in[0];
  const float* k  = (const float*)d_in[1];
  const float* v  = (const float*)d_in[2];
  const float* Wq = (const float*)d_in[3];
  const float* Wk = (const float*)d_in[4];
  const float* Wv = (const float*)d_in[5];
  const float* Wo = (const float*)d_in[6];
  const float* bq = (const float*)d_in[7];
  const float* bk = (const float*)d_in[8];
  const float* bv = (const float*)d_in[9];
  const float* bo = (const float*)d_in[10];

  constexpr size_t E_IN = (size_t)M_ * D_;
  constexpr size_t E_W  = (size_t)D_ * D_;
  char* ws = (char*)d_ws;
  size_t off = 0;
  bf16* Wqb = (bf16*)(ws + off); off += E_W * 2;
  bf16* Wkb = (bf16*)(ws + off); off += E_W * 2;
  bf16* Wvb = (bf16*)(ws + off); off += E_W * 2;
  bf16* Wob = (bf16*)(ws + off); off += E_W * 2;
  bf16* Qh  = (bf16*)(ws + off); off += E_IN * 2;
  bf16* Kh  = (bf16*)(ws + off); off += E_IN * 2;
  bf16* Vtw = (bf16*)(ws + off); off += E_IN * 2;
  bf16* ctx = (bf16*)(ws + off); off += E_IN * 2;

  // weights-only convert
  cvt_w<<<dim3(4096), dim3(256), 0, stream>>>(Wq, Wk, Wv, Wo, Wqb, Wkb, Wvb, Wob);

  // fused Q/K/V projections with T14-scheduled input conversion
  proj_qkv<<<dim3(32, 8, 3), dim3(512), 0, stream>>>(q, k, v, Wqb, Wkb, Wvb,
                                                     bq, bk, bv, Qh, Kh, Vtw);

  // causal attention -> ctx (B,T,D) bf16
  attn_fwd<<<dim3(1024), dim3(256), 0, stream>>>(Qh, Kh, Vtw, ctx);

  // output projection -> fp32 d_out
  gemm_out<<<dim3(32, 8), dim3(512), 0, stream>>>(ctx, Wob, bo, (float*)d_out);
}

// Round 12
// 191.844 us; speedup vs baseline: 1.1763x; 1.1763x over previous
//
#include <hip/hip_runtime.h>
#include <hip/hip_bf16.h>
#include <stdint.h>

#define B_ 4
#define T_ 2048
#define D_ 1024
#define H_ 16
#define DK_ 64
#define M_ (B_*T_)   // 8192

typedef __attribute__((ext_vector_type(8))) short bf16x8;
typedef __attribute__((ext_vector_type(4))) short bf16x4;
typedef __attribute__((ext_vector_type(4))) float f32x4;
typedef __hip_bfloat16 bf16;

__device__ __forceinline__ void gld_lds16(const bf16* g, bf16* l) {
  __builtin_amdgcn_global_load_lds((const __attribute__((address_space(1))) void*)g,
                                   (__attribute__((address_space(3))) void*)l,
                                   16, 0, 0);
}

__device__ __forceinline__ short bfbits(float f) {
  union { bf16 h; short s; } u; u.h = __float2bfloat16(f); return u.s;
}

// ---------------------------------------------------------------------------
// fused fp32 -> bf16 convert of all 7 tensors (round-8 exact)
// ---------------------------------------------------------------------------
__global__ __launch_bounds__(256) void cvt_all(
    const float* __restrict__ q, const float* __restrict__ k, const float* __restrict__ v,
    const float* __restrict__ wq, const float* __restrict__ wk,
    const float* __restrict__ wv, const float* __restrict__ wo,
    bf16* __restrict__ qb, bf16* __restrict__ kb, bf16* __restrict__ vb,
    bf16* __restrict__ wqb, bf16* __restrict__ wkb,
    bf16* __restrict__ wvb, bf16* __restrict__ wob) {
  int gid = blockIdx.x * 256 + threadIdx.x;   // 0 .. 7340031
  const float* src; bf16* dst; int off;
  if (gid < 6291456) {
    int s = gid >> 21; off = gid & 2097151;
    src = (s == 0) ? q : (s == 1) ? k : v;
    dst = (s == 0) ? qb : (s == 1) ? kb : vb;
  } else {
    int g2 = gid - 6291456;
    int s = g2 >> 18; off = g2 & 262143;
    src = (s == 0) ? wq : (s == 1) ? wk : (s == 2) ? wv : wo;
    dst = (s == 0) ? wqb : (s == 1) ? wkb : (s == 2) ? wvb : wob;
  }
  float4 val = reinterpret_cast<const float4*>(src)[off];
  union { ushort4 u; bf16 h[4]; } o;
  o.h[0] = __float2bfloat16(val.x);
  o.h[1] = __float2bfloat16(val.y);
  o.h[2] = __float2bfloat16(val.z);
  o.h[3] = __float2bfloat16(val.w);
  reinterpret_cast<ushort4*>(dst)[off] = o.u;
}

// ---------------------------------------------------------------------------
// Fused QKV projection GEMM, 256x128 tile, 512 threads (round-8 exact)
// ---------------------------------------------------------------------------
__global__ __launch_bounds__(512) void proj_qkv(
    const bf16* __restrict__ qb, const bf16* __restrict__ kb, const bf16* __restrict__ vb,
    const bf16* __restrict__ Wqb, const bf16* __restrict__ Wkb, const bf16* __restrict__ Wvb,
    const float* __restrict__ bq, const float* __restrict__ bk, const float* __restrict__ bv,
    bf16* __restrict__ Qh, bf16* __restrict__ Kh, bf16* __restrict__ Vt) {
  constexpr int K = 1024;
  constexpr int BK = 64;
  __shared__ __align__(16) bf16 As[256 * BK];
  __shared__ __align__(16) bf16 Bs[128 * BK];

  const int z = blockIdx.z;
  const bool vt = (z == 2);
  const bf16* A  = (z == 0) ? qb : (z == 1) ? kb : Wvb;
  const bf16* Bm = (z == 0) ? Wqb : (z == 1) ? Wkb : vb;
  const float* bias = (z == 0) ? bq : (z == 1) ? bk : bv;
  bf16* out = (z == 0) ? Qh : (z == 1) ? Kh : Vt;
  const float scale = (z == 0) ? 0.125f * 1.4426950408889634f : 1.0f;

  int bm, bn;
  if (vt) { int flat = blockIdx.x + 32 * blockIdx.y; bm = flat >> 6; bn = flat & 63; }
  else    { bm = blockIdx.x; bn = blockIdx.y; }

  const int tid = threadIdx.x;
  const int w = tid >> 6, l = tid & 63;
  const int wm = w >> 1, wn = w & 1;
  const int lr = l & 15, lk = l >> 4;

  f32x4 acc[4][4] = {};

  for (int k0 = 0; k0 < K; k0 += BK) {
#pragma unroll
    for (int i = 0; i < 4; ++i) {
      int p = i * 512 + tid;
      int row = p >> 3;
      int so = (p & 7) ^ (row & 7);
      gld_lds16(A + (size_t)(bm * 256 + row) * K + k0 + so * 8, &As[p * 8]);
    }
#pragma unroll
    for (int i = 0; i < 2; ++i) {
      int p = i * 512 + tid;
      int row = p >> 3;
      int so = (p & 7) ^ (row & 7);
      gld_lds16(Bm + (size_t)(bn * 128 + row) * K + k0 + so * 8, &Bs[p * 8]);
    }
    __syncthreads();

#pragma unroll
    for (int kk = 0; kk < 2; ++kk) {
      bf16x8 af[4], bfr[4];
#pragma unroll
      for (int m = 0; m < 4; ++m) {
        int row = wm * 64 + m * 16 + lr;
        int slot = (kk * 4 + lk) ^ (row & 7);
        af[m] = *reinterpret_cast<const bf16x8*>(&As[row * BK + slot * 8]);
      }
#pragma unroll
      for (int n = 0; n < 4; ++n) {
        int row = wn * 64 + n * 16 + lr;
        int slot = (kk * 4 + lk) ^ (row & 7);
        bfr[n] = *reinterpret_cast<const bf16x8*>(&Bs[row * BK + slot * 8]);
      }
#pragma unroll
      for (int m = 0; m < 4; ++m)
#pragma unroll
        for (int n = 0; n < 4; ++n)
          acc[m][n] = __builtin_amdgcn_mfma_f32_16x16x32_bf16(af[m], bfr[n], acc[m][n], 0, 0, 0);
    }
    __syncthreads();
  }

  const int crow0 = bm * 256 + wm * 64;
  const int ccol0 = bn * 128 + wn * 64;
#pragma unroll
  for (int m = 0; m < 4; ++m) {
#pragma unroll
    for (int n = 0; n < 4; ++n) {
#pragma unroll
      for (int r = 0; r < 4; ++r) {
        const int row = crow0 + m * 16 + lk * 4 + r;
        const int col = ccol0 + n * 16 + lr;
        if (!vt) {
          float vv = (acc[m][n][r] + bias[col]) * scale;
          size_t idx = (((size_t)(row >> 11) * H_ + (col >> 6)) * T_ + (row & (T_ - 1))) * DK_ + (col & (DK_ - 1));
          out[idx] = __float2bfloat16(vv);
        } else {
          float vv = acc[m][n][r] + bias[row];
          size_t idx = (size_t)(col >> 11) * ((size_t)H_ * DK_ * T_) + (size_t)row * T_ + (col & (T_ - 1));
          out[idx] = __float2bfloat16(vv);
        }
      }
    }
  }
}

// ---------------------------------------------------------------------------
// Output GEMM (fp32 out), 256x128 tile, 512 threads (round-8 exact)
// ---------------------------------------------------------------------------
__global__ __launch_bounds__(512) void gemm_out(const bf16* __restrict__ A,
                                                const bf16* __restrict__ Bm,
                                                const float* __restrict__ bias,
                                                float* __restrict__ Cout) {
  constexpr int K = 1024;
  constexpr int BK = 64;
  __shared__ __align__(16) bf16 As[256 * BK];
  __shared__ __align__(16) bf16 Bs[128 * BK];

  const int bm = blockIdx.x;
  const int bn = blockIdx.y;
  const int tid = threadIdx.x;
  const int w = tid >> 6, l = tid & 63;
  const int wm = w >> 1, wn = w & 1;
  const int lr = l & 15, lk = l >> 4;

  f32x4 acc[4][4] = {};

  for (int k0 = 0; k0 < K; k0 += BK) {
#pragma unroll
    for (int i = 0; i < 4; ++i) {
      int p = i * 512 + tid;
      int row = p >> 3;
      int so = (p & 7) ^ (row & 7);
      gld_lds16(A + (size_t)(bm * 256 + row) * K + k0 + so * 8, &As[p * 8]);
    }
#pragma unroll
    for (int i = 0; i < 2; ++i) {
      int p = i * 512 + tid;
      int row = p >> 3;
      int so = (p & 7) ^ (row & 7);
      gld_lds16(Bm + (size_t)(bn * 128 + row) * K + k0 + so * 8, &Bs[p * 8]);
    }
    __syncthreads();

#pragma unroll
    for (int kk = 0; kk < 2; ++kk) {
      bf16x8 af[4], bfr[4];
#pragma unroll
      for (int m = 0; m < 4; ++m) {
        int row = wm * 64 + m * 16 + lr;
        int slot = (kk * 4 + lk) ^ (row & 7);
        af[m] = *reinterpret_cast<const bf16x8*>(&As[row * BK + slot * 8]);
      }
#pragma unroll
      for (int n = 0; n < 4; ++n) {
        int row = wn * 64 + n * 16 + lr;
        int slot = (kk * 4 + lk) ^ (row & 7);
        bfr[n] = *reinterpret_cast<const bf16x8*>(&Bs[row * BK + slot * 8]);
      }
#pragma unroll
      for (int m = 0; m < 4; ++m)
#pragma unroll
        for (int n = 0; n < 4; ++n)
          acc[m][n] = __builtin_amdgcn_mfma_f32_16x16x32_bf16(af[m], bfr[n], acc[m][n], 0, 0, 0);
    }
    __syncthreads();
  }

  const int crow0 = bm * 256 + wm * 64;
  const int ccol0 = bn * 128 + wn * 64;
#pragma unroll
  for (int m = 0; m < 4; ++m) {
#pragma unroll
    for (int n = 0; n < 4; ++n) {
#pragma unroll
      for (int r = 0; r < 4; ++r) {
        const int row = crow0 + m * 16 + lk * 4 + r;
        const int col = ccol0 + n * 16 + lr;
        Cout[(size_t)row * D_ + col] = acc[m][n][r] + bias[col];
      }
    }
  }
}

// ---------------------------------------------------------------------------
// Causal flash attention v12: occupancy build — 7 blocks/CU.
// KVBLK=32, K/V double-buffered (LDS 21.5 KB total): Kbuf [32 kc][64 dk]
// (128B rows, 8-slot XOR); Vbuf packs 2 dk-rows per 128B LDS row
// ([row'=dk>>1][(dk&1)*64B + kc*2B], 8-slot XOR); Ps 80B-row per wave.
// Grid 2048 single-task blocks, heavy-first (t = 31 - bid>>6), head = bid&63
// keeps head%8 == bid%8 -> 8 heads/XCD (KV L2-pinned). Fixed-shift softmax.
// ---------------------------------------------------------------------------
__global__ __launch_bounds__(256, 7) void attn_fwd(const bf16* __restrict__ Qh,
                                                   const bf16* __restrict__ Kh,
                                                   const bf16* __restrict__ Vt,
                                                   bf16* __restrict__ ctx) {
  __shared__ __align__(16) bf16 Kbuf[2][32 * 64];   // 8 KB
  __shared__ __align__(16) bf16 Vbuf[2][32 * 64];   // 8 KB (packed 2 dk/row)
  __shared__ __align__(16) char Ps[4][16 * 80];     // 5 KB

  const int tid = threadIdx.x, w = tid >> 6, l = tid & 63;
  const int lr = l & 15, lk = l >> 4;
  const int bid = blockIdx.x;
  const int head = bid & 63;                 // head%8 == bid%8 -> XCD pinning
  const int t = 31 - (bid >> 6);             // heavy tasks dispatched first
  char* Pw = &Ps[w][0];

  const bf16* Qb = Qh + (size_t)head * T_ * DK_;
  const bf16* Kb = Kh + (size_t)head * T_ * DK_;
  const bf16* Vb = Vt + (size_t)head * DK_ * T_;
  const int bb = head >> 4, hh = head & 15;

  const int r0 = t * 64;
  const int nt32 = 2 * (t + 1);              // KV tiles of 32
  const int qrow = r0 + w * 16 + lr;
  const int jd = (r0 + w * 16) >> 5;         // this wave's diagonal tile

  const bf16* qp = Qb + (size_t)qrow * DK_ + lk * 8;
  bf16x8 qf0 = *reinterpret_cast<const bf16x8*>(qp);
  bf16x8 qf1 = *reinterpret_cast<const bf16x8*>(qp + 32);

  f32x4 oacc[4] = {};
  float srow = 0.f;

  // ---- prologue: stage tile 0 (each thread: 1 K chunk + 1 V chunk) ----
  {
    int p = tid;
    int krow = p >> 3;
    int kso = (p & 7) ^ (krow & 7);
    gld_lds16(Kb + (size_t)krow * DK_ + kso * 8, &Kbuf[0][p * 8]);
    int vrow = p >> 3;
    int u = (p & 7) ^ (vrow & 7);
    int dk = vrow * 2 + (u >> 2);
    gld_lds16(Vb + (size_t)dk * T_ + (u & 3) * 8, &Vbuf[0][p * 8]);
  }
  __syncthreads();

  int buf = 0;
#pragma unroll 1
  for (int j = 0; j < nt32; ++j) {
    // ---- issue next tile's staging (drained at the iteration-end barrier) ----
    if (j + 1 < nt32) {
      const int k0n = (j + 1) * 32;
      int p = tid;
      int krow = p >> 3;
      int kso = (p & 7) ^ (krow & 7);
      gld_lds16(Kb + (size_t)(k0n + krow) * DK_ + kso * 8, &Kbuf[buf ^ 1][p * 8]);
      int vrow = p >> 3;
      int u = (p & 7) ^ (vrow & 7);
      int dk = vrow * 2 + (u >> 2);
      gld_lds16(Vb + (size_t)dk * T_ + k0n + (u & 3) * 8, &Vbuf[buf ^ 1][p * 8]);
    }

    if (j <= jd) {   // wave-uniform skip beyond this wave's diagonal
      // ---- S^T = K Q^T : 2 frags (32 kc), 4 MFMA ----
      f32x4 sacc[2] = {};
      __builtin_amdgcn_s_setprio(1);
#pragma unroll
      for (int n = 0; n < 2; ++n) {
        int row = n * 16 + lr;
        int s0 = lk ^ (row & 7);
        int s1 = (4 + lk) ^ (row & 7);
        bf16x8 kf0 = *reinterpret_cast<const bf16x8*>(&Kbuf[buf][row * 64 + s0 * 8]);
        bf16x8 kf1 = *reinterpret_cast<const bf16x8*>(&Kbuf[buf][row * 64 + s1 * 8]);
        sacc[n] = __builtin_amdgcn_mfma_f32_16x16x32_bf16(kf0, qf0, sacc[n], 0, 0, 0);
        sacc[n] = __builtin_amdgcn_mfma_f32_16x16x32_bf16(kf1, qf1, sacc[n], 0, 0, 0);
      }
      __builtin_amdgcn_s_setprio(0);

      // ---- causal mask (diagonal tile only) ----
      if (j == jd) {
#pragma unroll
        for (int n = 0; n < 2; ++n)
#pragma unroll
          for (int r = 0; r < 4; ++r)
            if (j * 32 + n * 16 + lk * 4 + r > qrow) sacc[n][r] = -1e30f;
      }

      // ---- fixed-shift softmax: P = exp2(S) ----
      float ts = 0.f;
#pragma unroll
      for (int n = 0; n < 2; ++n) {
        float p0 = __builtin_exp2f(sacc[n][0]);
        float p1 = __builtin_exp2f(sacc[n][1]);
        float p2 = __builtin_exp2f(sacc[n][2]);
        float p3 = __builtin_exp2f(sacc[n][3]);
        ts += (p0 + p1) + (p2 + p3);
        bf16x4 pk;
        pk[0] = bfbits(p0); pk[1] = bfbits(p1); pk[2] = bfbits(p2); pk[3] = bfbits(p3);
        *reinterpret_cast<bf16x4*>(Pw + lr * 80 + n * 32 + lk * 8) = pk;
      }
      ts += __shfl_xor(ts, 16, 64);
      ts += __shfl_xor(ts, 32, 64);
      srow += ts;

      // ---- P fragment (B operand: col=lr, k = lk*8..lk*8+7 of 32) ----
      bf16x8 pa = *reinterpret_cast<const bf16x8*>(Pw + lr * 80 + lk * 16);

      // ---- O^T += V^T P^T : 4 MFMA ----
      __builtin_amdgcn_s_setprio(1);
#pragma unroll
      for (int n = 0; n < 4; ++n) {
        int rowp = n * 8 + (lr >> 1);                 // packed row' = dk>>1
        int u = (lr & 1) * 4 + lk;                    // unswizzled 16B slot
        int s = u ^ (rowp & 7);
        bf16x8 vf = *reinterpret_cast<const bf16x8*>(&Vbuf[buf][rowp * 64 + s * 8]);
        oacc[n] = __builtin_amdgcn_mfma_f32_16x16x32_bf16(vf, pa, oacc[n], 0, 0, 0);
      }
      __builtin_amdgcn_s_setprio(0);
    }

    __syncthreads();   // drains staged loads; protects buffer swap
    buf ^= 1;
  }

  // ---- normalize + packed store ----
  const float inv = 1.0f / srow;
#pragma unroll
  for (int n = 0; n < 4; ++n) {
    bf16x4 pk;
#pragma unroll
    for (int r = 0; r < 4; ++r) pk[r] = bfbits(oacc[n][r] * inv);
    *reinterpret_cast<bf16x4*>(&ctx[((size_t)(bb * T_ + qrow)) * D_ + hh * DK_ + n * 16 + lk * 4]) = pk;
  }
}

// ---------------------------------------------------------------------------
// launch
// ---------------------------------------------------------------------------
extern "C" void kernel_launch(void* const* d_in, const int* in_sizes, int n_in,
                              void* d_out, int out_size, void* d_ws, size_t ws_size,
                              hipStream_t stream) {
  const float* q  = (const float*)d_in[0];
  const float* k  = (const float*)d_in[1];
  const float* v  = (const float*)d_in[2];
  const float* Wq = (const float*)d_in[3];
  const float* Wk = (const float*)d_in[4];
  const float* Wv = (const float*)d_in[5];
  const float* Wo = (const float*)d_in[6];
  const float* bq = (const float*)d_in[7];
  const float* bk = (const float*)d_in[8];
  const float* bv = (const float*)d_in[9];
  const float* bo = (const float*)d_in[10];

  constexpr size_t E_IN = (size_t)M_ * D_;
  constexpr size_t E_W  = (size_t)D_ * D_;
  char* ws = (char*)d_ws;
  size_t off = 0;
  bf16* qb  = (bf16*)(ws + off); off += E_IN * 2;
  bf16* kb  = (bf16*)(ws + off); off += E_IN * 2;
  bf16* vb  = (bf16*)(ws + off); off += E_IN * 2;
  bf16* Wqb = (bf16*)(ws + off); off += E_W * 2;
  bf16* Wkb = (bf16*)(ws + off); off += E_W * 2;
  bf16* Wvb = (bf16*)(ws + off); off += E_W * 2;
  bf16* Wob = (bf16*)(ws + off); off += E_W * 2;
  bf16* Qh  = (bf16*)(ws + off); off += E_IN * 2;
  bf16* Kh  = (bf16*)(ws + off); off += E_IN * 2;
  bf16* Vtw = (bf16*)(ws + off); off += E_IN * 2;
  bf16* ctx = (bf16*)(ws + off); off += E_IN * 2;

  cvt_all<<<dim3(28672), dim3(256), 0, stream>>>(q, k, v, Wq, Wk, Wv, Wo,
                                                 qb, kb, vb, Wqb, Wkb, Wvb, Wob);

  proj_qkv<<<dim3(32, 8, 3), dim3(512), 0, stream>>>(qb, kb, vb, Wqb, Wkb, Wvb,
                                                     bq, bk, bv, Qh, Kh, Vtw);

  attn_fwd<<<dim3(2048), dim3(256), 0, stream>>>(Qh, Kh, Vtw, ctx);

  gemm_out<<<dim3(32, 8), dim3(512), 0, stream>>>(ctx, Wob, bo, (float*)d_out);
}